// Round 2
// baseline (1499.588 us; speedup 1.0000x reference)
//
#include <hip/hip_runtime.h>
#include <math.h>

#define B_TOT 2048
#define LSEQ  512
#define FDIM  64
#define G4    256   // 4*F

__device__ __forceinline__ float lane_bcast(float v, int i) {
    return __int_as_float(__builtin_amdgcn_readlane(__float_as_int(v), i));
}

__device__ __forceinline__ float sigm(float x) {
    return 1.0f / (1.0f + __expf(-x));
}

__device__ __forceinline__ float tanh_fast(float x) {
    // 1 - 2/(e^{2x}+1); saturates correctly at +/-1 for large |x|
    return 1.0f - 2.0f / (__expf(2.0f * x) + 1.0f);
}

__global__ __launch_bounds__(256, 1)
void lstm_logpsi_kernel(const int* __restrict__ s,
                        const float* __restrict__ W0,
                        const float* __restrict__ b0,
                        const float* __restrict__ Wi,
                        const float* __restrict__ Wh,
                        const float* __restrict__ bh,
                        const float* __restrict__ Wa,
                        const float* __restrict__ ba,
                        const float* __restrict__ Wp,
                        const float* __restrict__ bp,
                        float* __restrict__ out)
{
    const int lane = threadIdx.x & 63;
    const int wid  = threadIdx.x >> 6;           // wave within block: 0..3
    const int b    = blockIdx.x * 4 + wid;       // sample index

    __shared__ int sl[4][LSEQ];

    // ---- stage this wave's spin row into LDS (coalesced) ----
    const int* srow = s + b * LSEQ;
    #pragma unroll
    for (int k = 0; k < LSEQ / 64; ++k)
        sl[wid][k * 64 + lane] = srow[k * 64 + lane];
    __syncthreads();

    // ---- per-lane loop-invariant small weights ----
    const float wa0 = Wa[lane * 2 + 0];
    const float wa1 = Wa[lane * 2 + 1];
    const float wpv = Wp[lane];
    const float ba0 = ba[0];
    const float ba1 = ba[1];
    const float bpv = bp[0];

    // ---- precompute P[k][g] = (W0[k]+b0) @ Wi[:, g*64+lane] + bh[g*64+lane] ----
    // lane i holds (W0[k][i]+b0[i]); broadcast via readlane in the dot.
    const float w0b0 = W0[lane]        + b0[lane];   // k = 0
    const float w0b1 = W0[FDIM + lane] + b0[lane];   // k = 1
    float p0[4], p1[4];
    #pragma unroll
    for (int g = 0; g < 4; ++g) {
        float a0 = bh[g * 64 + lane];
        float a1 = a0;
        #pragma unroll
        for (int i = 0; i < FDIM; ++i) {
            float wi = Wi[i * G4 + g * 64 + lane];
            a0 = fmaf(lane_bcast(w0b0, i), wi, a0);
            a1 = fmaf(lane_bcast(w0b1, i), wi, a1);
        }
        p0[g] = a0;
        p1[g] = a1;
    }

    // ---- load this lane's 4 Wh columns into registers (256 VGPRs) ----
    float wh0[FDIM], wh1[FDIM], wh2[FDIM], wh3[FDIM];
    #pragma unroll
    for (int i = 0; i < FDIM; ++i) {
        wh0[i] = Wh[i * G4 +   0 + lane];
        wh1[i] = Wh[i * G4 +  64 + lane];
        wh2[i] = Wh[i * G4 + 128 + lane];
        wh3[i] = Wh[i * G4 + 192 + lane];
    }

    // ---- recurrence ----
    float h = 0.0f, c = 0.0f, amp = 0.0f;

    #pragma unroll 1
    for (int t = 0; t < LSEQ + 1; ++t) {
        const int tin = (t == 0) ? 0 : sl[wid][t - 1];

        float acc0 = tin ? p1[0] : p0[0];   // i gate
        float acc1 = tin ? p1[1] : p0[1];   // f gate
        float acc2 = tin ? p1[2] : p0[2];   // g gate
        float acc3 = tin ? p1[3] : p0[3];   // o gate

        #pragma unroll
        for (int i = 0; i < FDIM; ++i) {
            const float hb = lane_bcast(h, i);
            acc0 = fmaf(hb, wh0[i], acc0);
            acc1 = fmaf(hb, wh1[i], acc1);
            acc2 = fmaf(hb, wh2[i], acc2);
            acc3 = fmaf(hb, wh3[i], acc3);
        }

        const float ig = sigm(acc0);
        const float fg = sigm(acc1);
        const float gg = tanh_fast(acc2);
        const float og = sigm(acc3);
        c = fmaf(fg, c, ig * gg);
        h = og * tanh_fast(c);

        if (t < LSEQ) {
            // logits_k = sum_f h[f] * Wa[f][k] + ba[k]; K = 2
            float l0 = h * wa0;
            float l1 = h * wa1;
            #pragma unroll
            for (int m = 1; m < 64; m <<= 1) {
                l0 += __shfl_xor(l0, m, 64);
                l1 += __shfl_xor(l1, m, 64);
            }
            l0 += ba0;
            l1 += ba1;
            const int tgt = sl[wid][t];
            const float mx  = fmaxf(l0, l1);
            const float lse = mx + __logf(__expf(l0 - mx) + __expf(l1 - mx));
            amp += (tgt ? l1 : l0) - lse;
        }
    }

    // ---- phase = h_final @ Wp + bp ----
    float ph = h * wpv;
    #pragma unroll
    for (int m = 1; m < 64; m <<= 1)
        ph += __shfl_xor(ph, m, 64);
    ph += bpv;

    // Output layout: complex [B] flattened PLANAR — real block then imag block.
    if (lane == 0) {
        out[b]         = 0.5f * amp;   // LOG_PROB_FACTOR — real part
        out[B_TOT + b] = ph;           // imag part
    }
}

extern "C" void kernel_launch(void* const* d_in, const int* in_sizes, int n_in,
                              void* d_out, int out_size, void* d_ws, size_t ws_size,
                              hipStream_t stream) {
    const int*   s  = (const int*)  d_in[0];
    const float* W0 = (const float*)d_in[1];
    const float* b0 = (const float*)d_in[2];
    const float* Wi = (const float*)d_in[3];
    const float* Wh = (const float*)d_in[4];
    const float* bh = (const float*)d_in[5];
    const float* Wa = (const float*)d_in[6];
    const float* ba = (const float*)d_in[7];
    const float* Wp = (const float*)d_in[8];
    const float* bp = (const float*)d_in[9];
    float* out = (float*)d_out;

    dim3 grid(B_TOT / 4);
    dim3 block(256);
    lstm_logpsi_kernel<<<grid, block, 0, stream>>>(s, W0, b0, Wi, Wh, bh,
                                                   Wa, ba, Wp, bp, out);
}

// Round 3
// 751.272 us; speedup vs baseline: 1.9961x; 1.9961x over previous
//
#include <hip/hip_runtime.h>
#include <math.h>

typedef _Float16 f16x8 __attribute__((ext_vector_type(8)));
typedef float    f32x4 __attribute__((ext_vector_type(4)));

#define B_TOT 2048
#define LSEQ  512
#define NS    16      // samples per workgroup (= MFMA M)
#define TOKP  17      // padded token row stride (floats) — kills bank conflicts

__device__ __forceinline__ float sigm(float x) {
    return 1.0f / (1.0f + __expf(-x));
}
__device__ __forceinline__ float tanh_fast(float x) {
    return 1.0f - 2.0f / (__expf(2.0f * x) + 1.0f);
}

__global__ __launch_bounds__(256, 1)
void lstm_mfma_kernel(const int* __restrict__ s,
                      const float* __restrict__ W0,
                      const float* __restrict__ b0,
                      const float* __restrict__ Wi,
                      const float* __restrict__ Wh,
                      const float* __restrict__ bh,
                      const float* __restrict__ Wa,
                      const float* __restrict__ ba,
                      const float* __restrict__ Wp,
                      const float* __restrict__ bp,
                      float* __restrict__ out)
{
    const int tid  = threadIdx.x;
    const int w    = tid >> 6;    // wave 0..3 — owns feature tile ft=w (features 16w..16w+15)
    const int lane = tid & 63;
    const int n    = lane & 15;   // MFMA col-within-tile / A row
    const int q    = lane >> 4;   // quad
    const int b0s  = blockIdx.x * NS;

    // H: h in f16, rows=16 samples, row stride 72 f16 (144 B: 16B-aligned, bank-spread)
    __shared__ __align__(16) _Float16 Hh[2][16 * 72];
    __shared__ float TOK[513 * TOKP];   // time-major tokens as float; row 0 = pad token 0

    // ---- stage tokens ----
    if (tid < NS) TOK[tid] = 0.0f;
    for (int i = tid; i < NS * LSEQ; i += 256) {
        int m = i >> 9, t = i & (LSEQ - 1);
        TOK[(t + 1) * TOKP + m] = (float)s[(b0s + m) * LSEQ + t];
    }

    // ---- B-fragments of Wh in f16: B[k=8q+j+32c][col=64g+16w+n] ----
    f16x8 bwh[4][2];
    #pragma unroll
    for (int g = 0; g < 4; ++g) {
        const int col = 64 * g + 16 * w + n;
        #pragma unroll
        for (int c = 0; c < 2; ++c)
            #pragma unroll
            for (int j = 0; j < 8; ++j)
                bwh[g][c][j] = (_Float16)Wh[(32 * c + 8 * q + j) * 256 + col];
    }

    // ---- logits/phase fused B-fragment: col0=Wa[:,0], col1=Wa[:,1], col2=Wp ----
    f16x8 bwa[2];
    #pragma unroll
    for (int c = 0; c < 2; ++c)
        #pragma unroll
        for (int j = 0; j < 8; ++j) {
            int k = 32 * c + 8 * q + j;
            float v = (n == 0) ? Wa[k * 2] : (n == 1) ? Wa[k * 2 + 1]
                    : (n == 2) ? Wp[k] : 0.0f;
            bwa[c][j] = (_Float16)v;
        }
    const float bi = (n == 0) ? ba[0] : (n == 1) ? ba[1] : (n == 2) ? bp[0] : 0.0f;
    const f32x4 binit4 = {bi, bi, bi, bi};

    // ---- P0/dP: x@Wi + bh has only 2 values per column (one-hot input) ----
    float p0v[4], dpv[4];
    {
        float a0[4], a1[4];
        #pragma unroll
        for (int g = 0; g < 4; ++g) {
            float b = bh[64 * g + 16 * w + n];
            a0[g] = b; a1[g] = b;
        }
        for (int f = 0; f < 64; ++f) {
            float wb0 = W0[f]      + b0[f];
            float wb1 = W0[64 + f] + b0[f];
            #pragma unroll
            for (int g = 0; g < 4; ++g) {
                float wi = Wi[f * 256 + 64 * g + 16 * w + n];
                a0[g] = fmaf(wb0, wi, a0[g]);
                a1[g] = fmaf(wb1, wi, a1[g]);
            }
        }
        #pragma unroll
        for (int g = 0; g < 4; ++g) { p0v[g] = a0[g]; dpv[g] = a1[g] - a0[g]; }
    }

    __syncthreads();   // TOK ready

    // lane-local state: rows m = 4q+r, feature 16w+n
    float h4[4]   = {0, 0, 0, 0};
    float c4[4]   = {0, 0, 0, 0};
    float amp4[4] = {0, 0, 0, 0};
    f32x4 phacc   = {0, 0, 0, 0};

    #pragma unroll 1
    for (int u = 0; u <= 513; ++u) {
        const int p = u & 1;

        // publish h_{u-1} (D-layout -> LDS, f16)
        #pragma unroll
        for (int r = 0; r < 4; ++r)
            Hh[p][(4 * q + r) * 72 + 16 * w + n] = (_Float16)h4[r];
        __syncthreads();

        // A-fragments: A[m=n][k=8q+j(+32)]  — two 16B contiguous reads
        f16x8 af0 = *(const f16x8*)&Hh[p][n * 72 + 8 * q];
        f16x8 af1 = *(const f16x8*)&Hh[p][n * 72 + 32 + 8 * q];

        float tokf[4];
        if (u < 513) {
            #pragma unroll
            for (int r = 0; r < 4; ++r)
                tokf[r] = TOK[u * TOKP + 4 * q + r];
        }

        // wave0: fused logits+phase GEMM on h_{u-1}; target token == input token of step u
        if (w == 0 && u >= 1) {
            f32x4 accl = binit4;
            accl = __builtin_amdgcn_mfma_f32_16x16x32_f16(af0, bwa[0], accl, 0, 0, 0);
            accl = __builtin_amdgcn_mfma_f32_16x16x32_f16(af1, bwa[1], accl, 0, 0, 0);
            if (u <= 512) {
                #pragma unroll
                for (int r = 0; r < 4; ++r) {
                    float l  = accl[r];
                    float lx = __shfl_xor(l, 1, 64);   // n=0 gets l1, n=1 gets l0
                    if (n == 0) {
                        float mx  = fmaxf(l, lx);
                        float lse = mx + __logf(__expf(l - mx) + __expf(lx - mx));
                        amp4[r] += (tokf[r] != 0.0f ? lx : l) - lse;
                    }
                }
            } else {
                phacc = accl;   // u == 513: col2 = h_512@Wp + bp
            }
        }

        if (u <= 512) {
            // C-init = P0 + tok*dP (the whole x@Wi+bh GEMM), then 2 chained MFMAs per gate
            f32x4 acc0, acc1, acc2, acc3;
            #pragma unroll
            for (int r = 0; r < 4; ++r) {
                acc0[r] = fmaf(tokf[r], dpv[0], p0v[0]);
                acc1[r] = fmaf(tokf[r], dpv[1], p0v[1]);
                acc2[r] = fmaf(tokf[r], dpv[2], p0v[2]);
                acc3[r] = fmaf(tokf[r], dpv[3], p0v[3]);
            }
            acc0 = __builtin_amdgcn_mfma_f32_16x16x32_f16(af0, bwh[0][0], acc0, 0, 0, 0);
            acc0 = __builtin_amdgcn_mfma_f32_16x16x32_f16(af1, bwh[0][1], acc0, 0, 0, 0);
            acc1 = __builtin_amdgcn_mfma_f32_16x16x32_f16(af0, bwh[1][0], acc1, 0, 0, 0);
            acc1 = __builtin_amdgcn_mfma_f32_16x16x32_f16(af1, bwh[1][1], acc1, 0, 0, 0);
            acc2 = __builtin_amdgcn_mfma_f32_16x16x32_f16(af0, bwh[2][0], acc2, 0, 0, 0);
            acc2 = __builtin_amdgcn_mfma_f32_16x16x32_f16(af1, bwh[2][1], acc2, 0, 0, 0);
            acc3 = __builtin_amdgcn_mfma_f32_16x16x32_f16(af0, bwh[3][0], acc3, 0, 0, 0);
            acc3 = __builtin_amdgcn_mfma_f32_16x16x32_f16(af1, bwh[3][1], acc3, 0, 0, 0);

            // lane-local cell update for 4 rows
            #pragma unroll
            for (int r = 0; r < 4; ++r) {
                float ig = sigm(acc0[r]);
                float fg = sigm(acc1[r]);
                float gg = tanh_fast(acc2[r]);
                float og = sigm(acc3[r]);
                c4[r] = fmaf(fg, c4[r], ig * gg);
                h4[r] = og * tanh_fast(c4[r]);
            }
        }
    }

    // ---- output: planar complex [real(2048) | imag(2048)] ----
    if (w == 0) {
        #pragma unroll
        for (int r = 0; r < 4; ++r) {
            int m = 4 * q + r;
            if (n == 0) out[b0s + m]         = 0.5f * amp4[r];
            if (n == 2) out[B_TOT + b0s + m] = phacc[r];
        }
    }
}

extern "C" void kernel_launch(void* const* d_in, const int* in_sizes, int n_in,
                              void* d_out, int out_size, void* d_ws, size_t ws_size,
                              hipStream_t stream) {
    const int*   s  = (const int*)  d_in[0];
    const float* W0 = (const float*)d_in[1];
    const float* b0 = (const float*)d_in[2];
    const float* Wi = (const float*)d_in[3];
    const float* Wh = (const float*)d_in[4];
    const float* bh = (const float*)d_in[5];
    const float* Wa = (const float*)d_in[6];
    const float* ba = (const float*)d_in[7];
    const float* Wp = (const float*)d_in[8];
    const float* bp = (const float*)d_in[9];
    float* out = (float*)d_out;

    dim3 grid(B_TOT / NS);   // 128 workgroups
    dim3 block(256);         // 4 waves
    lstm_mfma_kernel<<<grid, block, 0, stream>>>(s, W0, b0, Wi, Wh, bh,
                                                 Wa, ba, Wp, bp, out);
}

// Round 4
// 626.608 us; speedup vs baseline: 2.3932x; 1.1990x over previous
//
#include <hip/hip_runtime.h>
#include <math.h>

typedef _Float16 f16x8 __attribute__((ext_vector_type(8)));
typedef float    f32x4 __attribute__((ext_vector_type(4)));

#define B_TOT 2048
#define LSEQ  512
#define NS    16    // samples per workgroup (= MFMA M)
#define HS    72    // Hh row stride in f16 (144 B: 16B-aligned, bank-spread)

__device__ __forceinline__ float sigm(float x) {
    return 1.0f / (1.0f + __expf(-x));
}
__device__ __forceinline__ float tanh_fast(float x) {
    return 1.0f - 2.0f / (__expf(2.0f * x) + 1.0f);
}

__global__ __launch_bounds__(256, 1)
void lstm_fused_kernel(const int* __restrict__ s,
                       const float* __restrict__ W0,
                       const float* __restrict__ b0,
                       const float* __restrict__ Wi,
                       const float* __restrict__ Wh,
                       const float* __restrict__ bh,
                       const float* __restrict__ Wa,
                       const float* __restrict__ ba,
                       const float* __restrict__ Wp,
                       const float* __restrict__ bp,
                       float* __restrict__ out)
{
    const int tid  = threadIdx.x;
    const int w    = tid >> 6;    // wave 0..3, owns gate cols 64g+16w+n
    const int lane = tid & 63;
    const int n    = lane & 15;
    const int q    = lane >> 4;
    const int b0s  = blockIdx.x * NS;

    __shared__ __align__(16) _Float16 Hh[2][NS * HS];
    __shared__ unsigned short TOKB[LSEQ + 2];     // TOKB[v] = bitmask of s[:, v-1]; TOKB[0]=0
    __shared__ unsigned char  SRAW[NS][LSEQ];
    __shared__ float AMP[4][NS];

    // ---- stage raw tokens (coalesced in t), then pack per-step 16-bit masks ----
    for (int i = tid; i < NS * LSEQ; i += 256)
        SRAW[i >> 9][i & 511] = (unsigned char)s[(b0s + (i >> 9)) * LSEQ + (i & 511)];
    __syncthreads();
    for (int u = tid; u <= LSEQ; u += 256) {
        unsigned int mask = 0;
        if (u >= 1) {
            #pragma unroll
            for (int m = 0; m < NS; ++m)
                mask |= ((unsigned int)SRAW[m][u - 1]) << m;
        }
        TOKB[u] = (unsigned short)mask;
    }

    // ---- B-fragments of Wh in f16: B[k=32c+8q+j][col=64g+16w+n] ----
    f16x8 bwh[4][2];
    #pragma unroll
    for (int g = 0; g < 4; ++g) {
        const int col = 64 * g + 16 * w + n;
        #pragma unroll
        for (int c = 0; c < 2; ++c)
            #pragma unroll
            for (int j = 0; j < 8; ++j)
                bwh[g][c][j] = (_Float16)Wh[(32 * c + 8 * q + j) * 256 + col];
    }

    // ---- lse/phase per-lane weights: lane covers feats 16q..16q+15 of sample n ----
    float wa0f[16], wa1f[16], wpf[16];
    #pragma unroll
    for (int j = 0; j < 16; ++j) {
        wa0f[j] = Wa[(16 * q + j) * 2 + 0];
        wa1f[j] = Wa[(16 * q + j) * 2 + 1];
        wpf[j]  = Wp[16 * q + j];
    }
    const float ba0 = ba[0], ba1 = ba[1], bpv = bp[0];

    // ---- P0/dP: x@Wi + bh has only 2 values per column (one-hot input) ----
    float p0v[4], dpv[4];
    {
        float a0[4], a1[4];
        #pragma unroll
        for (int g = 0; g < 4; ++g) {
            float bb = bh[64 * g + 16 * w + n];
            a0[g] = bb; a1[g] = bb;
        }
        for (int f = 0; f < 64; ++f) {
            float wb0 = W0[f]      + b0[f];
            float wb1 = W0[64 + f] + b0[f];
            #pragma unroll
            for (int g = 0; g < 4; ++g) {
                float wi = Wi[f * 256 + 64 * g + 16 * w + n];
                a0[g] = fmaf(wb0, wi, a0[g]);
                a1[g] = fmaf(wb1, wi, a1[g]);
            }
        }
        #pragma unroll
        for (int g = 0; g < 4; ++g) { p0v[g] = a0[g]; dpv[g] = a1[g] - a0[g]; }
    }

    __syncthreads();   // TOKB ready

    // ---- state ----
    float h4[4] = {0, 0, 0, 0}, c4[4] = {0, 0, 0, 0};
    float amp = 0.0f;
    unsigned int tokm = 0;     // TOKB[v] carried across iters (TOKB[0] = 0)
    f32x4 ci[4];               // pipelined C-init for current iter: ci[g][r]
    #pragma unroll
    for (int g = 0; g < 4; ++g) ci[g] = (f32x4){p0v[g], p0v[g], p0v[g], p0v[g]};

    #pragma unroll 1
    for (int v = 0; v <= LSEQ; ++v) {     // 513 gate steps; iter v consumes h_{v-1}
        const int p = v & 1;

        // publish h_{v-1}
        #pragma unroll
        for (int r = 0; r < 4; ++r)
            Hh[p][(4 * q + r) * HS + 16 * w + n] = (_Float16)h4[r];
        __syncthreads();

        // A-fragments of h_{v-1}
        f16x8 af0 = *(const f16x8*)&Hh[p][n * HS + 8 * q];
        f16x8 af1 = *(const f16x8*)&Hh[p][n * HS + 32 + 8 * q];

        // prefetch next step's token mask (off-chain)
        const unsigned int tokm_next = (v < LSEQ) ? (unsigned int)TOKB[v + 1] : 0u;

        // gates GEMM: C-init was precomputed last iter
        f32x4 acc0 = ci[0], acc1 = ci[1], acc2 = ci[2], acc3 = ci[3];
        acc0 = __builtin_amdgcn_mfma_f32_16x16x32_f16(af0, bwh[0][0], acc0, 0, 0, 0);
        acc1 = __builtin_amdgcn_mfma_f32_16x16x32_f16(af0, bwh[1][0], acc1, 0, 0, 0);
        acc2 = __builtin_amdgcn_mfma_f32_16x16x32_f16(af0, bwh[2][0], acc2, 0, 0, 0);
        acc3 = __builtin_amdgcn_mfma_f32_16x16x32_f16(af0, bwh[3][0], acc3, 0, 0, 0);
        acc0 = __builtin_amdgcn_mfma_f32_16x16x32_f16(af1, bwh[0][1], acc0, 0, 0, 0);
        acc1 = __builtin_amdgcn_mfma_f32_16x16x32_f16(af1, bwh[1][1], acc1, 0, 0, 0);
        acc2 = __builtin_amdgcn_mfma_f32_16x16x32_f16(af1, bwh[2][1], acc2, 0, 0, 0);
        acc3 = __builtin_amdgcn_mfma_f32_16x16x32_f16(af1, bwh[3][1], acc3, 0, 0, 0);

        // C-init for NEXT iter (fills the MFMA shadow; depends only on tokm_next)
        #pragma unroll
        for (int r = 0; r < 4; ++r) {
            float bf = ((tokm_next >> (4 * q + r)) & 1) ? 1.0f : 0.0f;
            #pragma unroll
            for (int g = 0; g < 4; ++g)
                ci[g][r] = fmaf(bf, dpv[g], p0v[g]);
        }

        // rotating lse: wave (v&3) handles step v (h_{v-1} in Hh[p], target = TOKB[v])
        if (v >= 1 && w == (v & 3)) {
            const _Float16* hp = &Hh[p][n * HS + 16 * q];
            f16x8 hh0 = *(const f16x8*)hp;
            f16x8 hh1 = *(const f16x8*)(hp + 8);
            float l0 = 0.0f, l1 = 0.0f;
            #pragma unroll
            for (int j = 0; j < 8; ++j) {
                float a = (float)hh0[j], b2 = (float)hh1[j];
                l0 = fmaf(a, wa0f[j], fmaf(b2, wa0f[j + 8], l0));
                l1 = fmaf(a, wa1f[j], fmaf(b2, wa1f[j + 8], l1));
            }
            l0 += __shfl_xor(l0, 16, 64);  l0 += __shfl_xor(l0, 32, 64);
            l1 += __shfl_xor(l1, 16, 64);  l1 += __shfl_xor(l1, 32, 64);
            l0 += ba0;  l1 += ba1;
            float mx  = fmaxf(l0, l1);
            float lse = mx + __logf(__expf(l0 - mx) + __expf(l1 - mx));
            amp += (((tokm >> n) & 1) ? l1 : l0) - lse;
        }

        // cell update (lane-local, 4 samples)
        #pragma unroll
        for (int r = 0; r < 4; ++r) {
            float ig = sigm(acc0[r]);
            float fg = sigm(acc1[r]);
            float gg = tanh_fast(acc2[r]);
            float og = sigm(acc3[r]);
            c4[r] = fmaf(fg, c4[r], ig * gg);
            h4[r] = og * tanh_fast(c4[r]);
        }

        tokm = tokm_next;
    }

    // ---- tail: publish h_512, combine amp quarters, compute phase ----
    #pragma unroll
    for (int r = 0; r < 4; ++r)
        Hh[(LSEQ + 1) & 1][(4 * q + r) * HS + 16 * w + n] = (_Float16)h4[r];
    if (q == 0) AMP[w][n] = amp;     // all q-copies of amp are identical post-reduce
    __syncthreads();

    if (w == 0) {
        const _Float16* hp = &Hh[(LSEQ + 1) & 1][n * HS + 16 * q];
        f16x8 hh0 = *(const f16x8*)hp;
        f16x8 hh1 = *(const f16x8*)(hp + 8);
        float phl = 0.0f;
        #pragma unroll
        for (int j = 0; j < 8; ++j)
            phl = fmaf((float)hh0[j], wpf[j], fmaf((float)hh1[j], wpf[j + 8], phl));
        phl += __shfl_xor(phl, 16, 64);
        phl += __shfl_xor(phl, 32, 64);
        if (q == 0) {
            float ampsum = AMP[0][n] + AMP[1][n] + AMP[2][n] + AMP[3][n];
            out[b0s + n]         = 0.5f * ampsum;   // LOG_PROB_FACTOR — real (planar)
            out[B_TOT + b0s + n] = phl + bpv;       // imag (planar)
        }
    }
}

extern "C" void kernel_launch(void* const* d_in, const int* in_sizes, int n_in,
                              void* d_out, int out_size, void* d_ws, size_t ws_size,
                              hipStream_t stream) {
    const int*   s  = (const int*)  d_in[0];
    const float* W0 = (const float*)d_in[1];
    const float* b0 = (const float*)d_in[2];
    const float* Wi = (const float*)d_in[3];
    const float* Wh = (const float*)d_in[4];
    const float* bh = (const float*)d_in[5];
    const float* Wa = (const float*)d_in[6];
    const float* ba = (const float*)d_in[7];
    const float* Wp = (const float*)d_in[8];
    const float* bp = (const float*)d_in[9];
    float* out = (float*)d_out;

    dim3 grid(B_TOT / NS);   // 128 workgroups, latency-bound: chain length is what matters
    dim3 block(256);
    lstm_fused_kernel<<<grid, block, 0, stream>>>(s, W0, b0, Wi, Wh, bh,
                                                  Wa, ba, Wp, bp, out);
}

// Round 5
// 348.382 us; speedup vs baseline: 4.3044x; 1.7986x over previous
//
#include <hip/hip_runtime.h>
#include <math.h>

typedef _Float16 f16x8 __attribute__((ext_vector_type(8)));
typedef _Float16 f16x4 __attribute__((ext_vector_type(4)));
typedef float    f32x4 __attribute__((ext_vector_type(4)));

#define B_TOT 2048
#define LSEQ  512
#define NS    16          // samples per workgroup (MFMA N)
#define HS    88          // f16 per sample row of Hh (176 B: 16B-mult, conflict-benign)
#define LOG2E 1.44269504088896f
#define LN2   0.69314718055995f

#define MFMA16(A, B, C) __builtin_amdgcn_mfma_f32_16x16x32_f16((A), (B), (C), 0, 0, 0)

__global__ __launch_bounds__(256, 1)
void lstm_gt_kernel(const int* __restrict__ s,
                    const float* __restrict__ W0, const float* __restrict__ b0,
                    const float* __restrict__ Wi, const float* __restrict__ Wh,
                    const float* __restrict__ bh, const float* __restrict__ Wa,
                    const float* __restrict__ ba, const float* __restrict__ Wp,
                    const float* __restrict__ bp, float* __restrict__ out)
{
    const int tid  = threadIdx.x;
    const int w    = tid >> 6;     // wave 0..3: owns feature block 16w..16w+15 (tiles 4g+w)
    const int lane = tid & 63;
    const int n    = lane & 15;    // sample index (MFMA N / B-col / D-col)
    const int q    = lane >> 4;

    const int b0s  = blockIdx.x * NS;

    __shared__ __align__(16) _Float16 Hh[2][NS * HS];   // sample-major h, f16
    __shared__ unsigned short TOKB[LSEQ + 2];
    __shared__ unsigned char  SRAW[NS][LSEQ];
    __shared__ float DBUF[LSEQ][NS];                    // raw logit-diffs, post-processed
    __shared__ float PART[16][NS];

    // ---- stage tokens ----
    for (int i = tid; i < NS * LSEQ; i += 256)
        SRAW[i >> 9][i & 511] = (unsigned char)s[(b0s + (i >> 9)) * LSEQ + (i & 511)];
    __syncthreads();
    for (int u = tid; u <= LSEQ; u += 256) {
        unsigned int mask = 0;
        if (u >= 1) {
            #pragma unroll
            for (int m = 0; m < NS; ++m)
                mask |= ((unsigned int)SRAW[m][u - 1]) << m;
        }
        TOKB[u] = (unsigned short)mask;
    }

    // ---- A-frags: scaled Wh^T. Wave w, gate g -> tile T=4g+w (cols 64g+16w..+15).
    // lane (n,q): A[m=n][k=32c+8q+j] = scale_g * Wh[32c+8q+j][64g+16w+n]
    f16x8 awh[4][2];
    #pragma unroll
    for (int g = 0; g < 4; ++g) {
        const float sc  = (g == 2) ? (2.0f * LOG2E) : (-LOG2E);
        const int   col = 64 * g + 16 * w + n;
        #pragma unroll
        for (int c = 0; c < 2; ++c)
            #pragma unroll
            for (int j = 0; j < 8; ++j)
                awh[g][c][j] = (_Float16)(Wh[(32 * c + 8 * q + j) * 256 + col] * sc);
    }

    // ---- d-GEMM A-frag: row 0 = Wa[:,1]-Wa[:,0], other rows 0 (unscaled) ----
    f16x8 awd[2];
    #pragma unroll
    for (int c = 0; c < 2; ++c)
        #pragma unroll
        for (int j = 0; j < 8; ++j) {
            int k = 32 * c + 8 * q + j;
            awd[c][j] = (_Float16)((n == 0) ? (Wa[2 * k + 1] - Wa[2 * k]) : 0.0f);
        }
    const float dba = ba[1] - ba[0];

    // ---- p0/dp (scaled): cols col[g][r] = 64g+16w+4q+r ----
    float p0v[4][4], dpv[4][4];
    {
        float a0[4][4], a1[4][4];
        #pragma unroll
        for (int g = 0; g < 4; ++g)
            #pragma unroll
            for (int r = 0; r < 4; ++r) {
                float bb = bh[64 * g + 16 * w + 4 * q + r];
                a0[g][r] = bb; a1[g][r] = bb;
            }
        for (int f = 0; f < 64; ++f) {
            float wb0 = W0[f]      + b0[f];
            float wb1 = W0[64 + f] + b0[f];
            #pragma unroll
            for (int g = 0; g < 4; ++g) {
                const float4 wi4 = *(const float4*)&Wi[f * 256 + 64 * g + 16 * w + 4 * q];
                #pragma unroll
                for (int r = 0; r < 4; ++r) {
                    float wi = (&wi4.x)[r];
                    a0[g][r] = fmaf(wb0, wi, a0[g][r]);
                    a1[g][r] = fmaf(wb1, wi, a1[g][r]);
                }
            }
        }
        #pragma unroll
        for (int g = 0; g < 4; ++g) {
            const float sc = (g == 2) ? (2.0f * LOG2E) : (-LOG2E);
            #pragma unroll
            for (int r = 0; r < 4; ++r) {
                p0v[g][r] = a0[g][r] * sc;
                dpv[g][r] = (a1[g][r] - a0[g][r]) * sc;
            }
        }
    }

    __syncthreads();   // TOKB ready

    // ---- state: lane (n,q) of wave w: sample n, features 16w+4q+r ----
    float h4[4] = {0, 0, 0, 0}, c4[4] = {0, 0, 0, 0};
    f32x4 ci[4];
    #pragma unroll
    for (int g = 0; g < 4; ++g)
        ci[g] = (f32x4){p0v[g][0], p0v[g][1], p0v[g][2], p0v[g][3]};

    #pragma unroll 1
    for (int v = 0; v <= LSEQ; ++v) {
        const int p = v & 1;

        // publish h_{v-1}: 4 consecutive features, one b64 write
        f16x4 hv;
        #pragma unroll
        for (int r = 0; r < 4; ++r) hv[r] = (_Float16)h4[r];
        *(f16x4*)&Hh[p][n * HS + 16 * w + 4 * q] = hv;
        __syncthreads();

        // B-frags: B[k=8q+j(+32)][sample n] = h[n][feature]
        f16x8 bf0 = *(const f16x8*)&Hh[p][n * HS + 8 * q];
        f16x8 bf1 = *(const f16x8*)&Hh[p][n * HS + 32 + 8 * q];

        const unsigned int tokm_next = (v < LSEQ) ? (unsigned int)TOKB[v + 1] : 0u;

        // gates GEMM (G^T): D[gate-col 16T+4q+r][sample n]
        f32x4 acc0 = ci[0], acc1 = ci[1], acc2 = ci[2], acc3 = ci[3];
        acc0 = MFMA16(awh[0][0], bf0, acc0);
        acc1 = MFMA16(awh[1][0], bf0, acc1);
        acc2 = MFMA16(awh[2][0], bf0, acc2);
        acc3 = MFMA16(awh[3][0], bf0, acc3);
        acc0 = MFMA16(awh[0][1], bf1, acc0);
        acc1 = MFMA16(awh[1][1], bf1, acc1);
        acc2 = MFMA16(awh[2][1], bf1, acc2);
        acc3 = MFMA16(awh[3][1], bf1, acc3);

        // rotating wave: raw logit-diff d for step v-1 via one MFMA pair; defer softplus
        if (v >= 1 && w == (v & 3)) {
            f32x4 da = (f32x4){dba, dba, dba, dba};
            da = MFMA16(awd[0], bf0, da);
            da = MFMA16(awd[1], bf1, da);
            if (lane < 16) DBUF[v - 1][n] = da[0];   // row 0 lives in q=0, reg 0
        }

        // C-init for next iter (token of sample n, uniform across r)
        const float sel = (float)((tokm_next >> n) & 1u);
        #pragma unroll
        for (int g = 0; g < 4; ++g)
            #pragma unroll
            for (int r = 0; r < 4; ++r)
                ci[g][r] = fmaf(sel, dpv[g][r], p0v[g][r]);

        // activations: prefolded exp2 units; combined reciprocals
        #pragma unroll
        for (int r = 0; r < 4; ++r) {
            float ei = __builtin_amdgcn_exp2f(acc0[r]);               // e^{-i}
            float ef = __builtin_amdgcn_exp2f(acc1[r]);               // e^{-f}
            float eg = __builtin_amdgcn_exp2f(fminf(acc2[r], 60.f));  // e^{2g}
            float eo = __builtin_amdgcn_exp2f(acc3[r]);               // e^{-o}
            float Rf  = __builtin_amdgcn_rcpf(1.0f + ef);
            float Rig = __builtin_amdgcn_rcpf((1.0f + ei) * (eg + 1.0f));
            float cn  = fmaf(c4[r], Rf, (eg - 1.0f) * Rig);
            c4[r] = cn;
            float ec = __builtin_amdgcn_exp2f(fminf(cn * (2.0f * LOG2E), 60.f));
            float Ro = __builtin_amdgcn_rcpf((1.0f + eo) * (ec + 1.0f));
            h4[r] = (ec - 1.0f) * Ro;
        }
    }

    // ---- tail: publish h_512, then post-process amp (softplus pass) + phase ----
    {
        f16x4 hv;
        #pragma unroll
        for (int r = 0; r < 4; ++r) hv[r] = (_Float16)h4[r];
        *(f16x4*)&Hh[1][n * HS + 16 * w + 4 * q] = hv;
    }
    __syncthreads();   // DBUF + final Hh complete

    // amp: amp_n = -sum_t softplus(tgt ? -d : d); out = 0.5*amp
    {
        const int nn = tid & 15;
        const int ch = tid >> 4;           // 16 chunks of 32 steps
        float a = 0.0f;
        #pragma unroll 4
        for (int k = 0; k < 32; ++k) {
            int t = ch * 32 + k;
            float d = DBUF[t][nn];
            float x = SRAW[nn][t] ? -d : d;
            float e = __builtin_amdgcn_exp2f(-fabsf(x) * LOG2E);
            a += fmaxf(x, 0.0f) + __builtin_amdgcn_logf(1.0f + e) * LN2;
        }
        PART[ch][nn] = a;
    }
    __syncthreads();

    if (tid < 16) {
        float ssum = 0.0f;
        #pragma unroll
        for (int c = 0; c < 16; ++c) ssum += PART[c][tid];
        out[b0s + tid] = -0.5f * ssum;     // LOG_PROB_FACTOR, planar real
    }

    // phase = h_512 @ Wp + bp
    if (w == 0) {
        const _Float16* hp = &Hh[1][n * HS + 16 * q];
        f16x8 h0 = *(const f16x8*)hp;
        f16x8 h1 = *(const f16x8*)(hp + 8);
        float ph = 0.0f;
        #pragma unroll
        for (int j = 0; j < 8; ++j)
            ph = fmaf((float)h0[j], Wp[16 * q + j],
                 fmaf((float)h1[j], Wp[16 * q + j + 8], ph));
        ph += __shfl_xor(ph, 16, 64);
        ph += __shfl_xor(ph, 32, 64);
        if (q == 0) out[B_TOT + b0s + n] = ph + bp[0];   // planar imag
    }
}

extern "C" void kernel_launch(void* const* d_in, const int* in_sizes, int n_in,
                              void* d_out, int out_size, void* d_ws, size_t ws_size,
                              hipStream_t stream) {
    const int*   s  = (const int*)  d_in[0];
    const float* W0 = (const float*)d_in[1];
    const float* b0 = (const float*)d_in[2];
    const float* Wi = (const float*)d_in[3];
    const float* Wh = (const float*)d_in[4];
    const float* bh = (const float*)d_in[5];
    const float* Wa = (const float*)d_in[6];
    const float* ba = (const float*)d_in[7];
    const float* Wp = (const float*)d_in[8];
    const float* bp = (const float*)d_in[9];
    float* out = (float*)d_out;

    dim3 grid(B_TOT / NS);   // 128 workgroups; latency-bound -> chain length is king
    dim3 block(256);
    lstm_gt_kernel<<<grid, block, 0, stream>>>(s, W0, b0, Wi, Wh, bh,
                                               Wa, ba, Wp, bp, out);
}